// Round 4
// baseline (189.909 us; speedup 1.0000x reference)
//
#include <hip/hip_runtime.h>
#include <hip/hip_bf16.h>

// IsometricLoss: loss = (1/N) * sum_{i,m} r[i,m] * max(||X_i||^2 + ||mu_m||^2 - 2 X_i.mu_m, 0)
// N=131072, M=128, D=128, fp32 in, fp32 scalar out.
//
// R4: software-pipelined 32-row groups (4 iters/block), double-buffered LDS,
// prefetch-in-regs across an lgkm-only barrier (global loads stay in flight).
// MFMA operands swapped vs R1-R3 (A=mus, B=X^T): D[mu][i] with i=lane&31, so
// r loads are 4x float4 per iter (was 16 scalars) and x2 is one LDS broadcast.

typedef __attribute__((ext_vector_type(8)))  short  short8;   // 8 bf16 (MFMA A/B frag)
typedef __attribute__((ext_vector_type(16))) float  float16v; // MFMA 32x32 accumulator

#define LDSP 136  // padded LDS row stride (bf16 elems); 272 B row pitch, 16B-aligned

#if defined(__has_builtin)
#if __has_builtin(__builtin_amdgcn_cvt_pk_bf16_f32)
#define HAVE_PK_BF16 1
#endif
#endif

__device__ __forceinline__ unsigned int pk_bf16(float x, float y) {
#ifdef HAVE_PK_BF16
    typedef __attribute__((ext_vector_type(2))) __bf16 bf16x2;
    bf16x2 p = __builtin_amdgcn_cvt_pk_bf16_f32(x, y);
    return __builtin_bit_cast(unsigned int, p);
#else
    unsigned int ux = __float_as_uint(x);
    unsigned int uy = __float_as_uint(y);
    ux += 0x7fffu + ((ux >> 16) & 1u);
    uy += 0x7fffu + ((uy >> 16) & 1u);
    return (ux >> 16) | (uy & 0xffff0000u);
#endif
}

// Barrier that does NOT drain vmcnt: global loads -> private VGPRs need no
// cross-wave visibility; only LDS writes (lgkmcnt) must be visible.
// waitcnt simm16: vmcnt[3:0]=0xF,[15:14]=3 (=63, unconstrained), expcnt[6:4]=7,
// lgkmcnt[11:8]=0  => 0xC07F.
__device__ __forceinline__ void barrier_lgkm_only() {
    asm volatile("" ::: "memory");
    __builtin_amdgcn_s_waitcnt(0xC07F);
    __builtin_amdgcn_s_barrier();
    asm volatile("" ::: "memory");
}

__global__ void zero_ws_kernel(float* ws) { ws[threadIdx.x] = 0.0f; }  // 64 buckets

__global__ void final_reduce_kernel(const float* ws, float* out) {
    const int lane = threadIdx.x;  // 64 threads
    float t = ws[lane];
    #pragma unroll
    for (int off = 32; off > 0; off >>= 1) t += __shfl_down(t, off);
    if (lane == 0) out[0] = t * (1.0f / 131072.0f);
}

__global__ __launch_bounds__(256, 4)
void isoloss_kernel(const float* __restrict__ X,
                    const float* __restrict__ r,
                    const float* __restrict__ mus,
                    float* __restrict__ ws)
{
    const int tid  = threadIdx.x;
    const int blk  = blockIdx.x;     // handles row groups blk*4 .. blk*4+3 (32 rows each)
    const int wave = tid >> 6;       // 0..3 -> which 32-mu tile this wave owns
    const int lane = tid & 63;
    const int col  = lane & 31;      // = row index i within group (D's n-dim)
    const int half = lane >> 5;

    __shared__ unsigned short ldsA[2][32 * LDSP]; // X tile bf16, double-buffered (~17 KB)
    __shared__ float x2s[2][32];
    __shared__ float wsum[4];

    // ---- one-time: B... now A fragments = this wave's 32 mus + exact fp32 mu2 ----
    // frag: lane holds mus[wave*32+col][ks*16 + half*8 + j], j=0..7  (A m-dim = mu)
    short8 bfrag[8];
    float mu2p = 0.0f;
    {
        const float* mrow = mus + (size_t)(wave * 32 + col) * 128 + half * 8;
        #pragma unroll
        for (int ks = 0; ks < 8; ++ks) {
            const float4 a = *(const float4*)(mrow + ks * 16);
            const float4 b = *(const float4*)(mrow + ks * 16 + 4);
            mu2p += a.x*a.x + a.y*a.y + a.z*a.z + a.w*a.w
                  + b.x*b.x + b.y*b.y + b.z*b.z + b.w*b.w;
            union { short8 s8; uint4 u4; } u;
            u.u4.x = pk_bf16(a.x, a.y);
            u.u4.y = pk_bf16(a.z, a.w);
            u.u4.z = pk_bf16(b.x, b.y);
            u.u4.w = pk_bf16(b.z, b.w);
            bfrag[ks] = u.s8;
        }
    }
    const float mu2 = mu2p + __shfl_xor(mu2p, 32);  // lane holds mu2[wave*32+col]
    // epilogue needs mu2 for mus {q*8 + half*4 + j}: gather once via shuffles
    float4 mu2q[4];
    #pragma unroll
    for (int q = 0; q < 4; ++q) {
        mu2q[q].x = __shfl(mu2, q * 8 + half * 4 + 0);
        mu2q[q].y = __shfl(mu2, q * 8 + half * 4 + 1);
        mu2q[q].z = __shfl(mu2, q * 8 + half * 4 + 2);
        mu2q[q].w = __shfl(mu2, q * 8 + half * 4 + 3);
    }

    const int g0 = blk * 4;  // first group
    // ---- prologue: prefetch group 0 (X and r) into registers ----
    float4 xv[4], rv[4];
    {
        const float* xb = X + (size_t)g0 * 32 * 128;
        #pragma unroll
        for (int j = 0; j < 4; ++j)
            xv[j] = *(const float4*)(xb + (size_t)(j * 256 + tid) * 4);
        const float* rb = r + (size_t)(g0 * 32 + col) * 128 + wave * 32 + half * 4;
        #pragma unroll
        for (int q = 0; q < 4; ++q)
            rv[q] = *(const float4*)(rb + q * 8);
    }

    float s = 0.0f;

    #pragma unroll
    for (int g = 0; g < 4; ++g) {
        const int buf = g & 1;

        // ---- stage X(g) from regs -> bf16 LDS + exact fp32 x2 ----
        #pragma unroll
        for (int j = 0; j < 4; ++j) {
            const float4 v = xv[j];
            float p = v.x*v.x + v.y*v.y + v.z*v.z + v.w*v.w;
            p += __shfl_xor(p, 16);
            p += __shfl_xor(p, 8);
            p += __shfl_xor(p, 4);
            p += __shfl_xor(p, 2);
            p += __shfl_xor(p, 1);
            const int row = j * 8 + (tid >> 5);
            if ((tid & 31) == 0) x2s[buf][row] = p;
            uint2 h;
            h.x = pk_bf16(v.x, v.y);
            h.y = pk_bf16(v.z, v.w);
            *(uint2*)&ldsA[buf][row * LDSP + (tid & 31) * 4] = h;
        }

        // ---- prefetch X(g+1): issued before the barrier, stays in flight ----
        if (g < 3) {
            const float* xb = X + (size_t)(g0 + g + 1) * 32 * 128;
            #pragma unroll
            for (int j = 0; j < 4; ++j)
                xv[j] = *(const float4*)(xb + (size_t)(j * 256 + tid) * 4);
        }

        barrier_lgkm_only();  // LDS writes visible; global loads NOT drained

        // ---- 8x MFMA: D[mu][i], A=mus (regs), B=X^T (LDS) ----
        float16v acc = {};
        #pragma unroll
        for (int ks = 0; ks < 8; ++ks) {
            const short8 af = *(const short8*)&ldsA[buf][col * LDSP + ks * 16 + half * 8];
            acc = __builtin_amdgcn_mfma_f32_32x32x16_bf16(bfrag[ks], af, acc, 0, 0, 0);
        }

        // ---- epilogue: i = col (lane), mu = (reg&3)+8*(reg>>2)+4*half ----
        const float x2r = x2s[buf][col];
        #pragma unroll
        for (int q = 0; q < 4; ++q) {
            const float4 rq = rv[q];
            const float4 m2 = mu2q[q];
            s += rq.x * fmaxf(x2r + m2.x - 2.0f * acc[q * 4 + 0], 0.0f);
            s += rq.y * fmaxf(x2r + m2.y - 2.0f * acc[q * 4 + 1], 0.0f);
            s += rq.z * fmaxf(x2r + m2.z - 2.0f * acc[q * 4 + 2], 0.0f);
            s += rq.w * fmaxf(x2r + m2.w - 2.0f * acc[q * 4 + 3], 0.0f);
        }

        // ---- prefetch r(g+1): long lead (next staging+barrier+MFMA) ----
        if (g < 3) {
            const float* rb = r + (size_t)((g0 + g + 1) * 32 + col) * 128 + wave * 32 + half * 4;
            #pragma unroll
            for (int q = 0; q < 4; ++q)
                rv[q] = *(const float4*)(rb + q * 8);
        }
    }

    // ---- reduce: wave shuffle -> block -> bucketed atomic ----
    #pragma unroll
    for (int off = 32; off > 0; off >>= 1) s += __shfl_down(s, off);
    if (lane == 0) wsum[wave] = s;
    __syncthreads();
    if (tid == 0)
        atomicAdd(&ws[blk & 63], wsum[0] + wsum[1] + wsum[2] + wsum[3]);
}

extern "C" void kernel_launch(void* const* d_in, const int* in_sizes, int n_in,
                              void* d_out, int out_size, void* d_ws, size_t ws_size,
                              hipStream_t stream) {
    const float* X   = (const float*)d_in[0];   // [131072, 128]
    const float* r   = (const float*)d_in[1];   // [131072, 128]
    const float* mus = (const float*)d_in[2];   // [128, 128]
    float* out = (float*)d_out;                 // scalar
    float* ws  = (float*)d_ws;                  // 64 partial buckets

    zero_ws_kernel<<<1, 64, 0, stream>>>(ws);
    isoloss_kernel<<<1024, 256, 0, stream>>>(X, r, mus, ws);
    final_reduce_kernel<<<1, 64, 0, stream>>>(ws, out);
}

// Round 5
// 165.064 us; speedup vs baseline: 1.1505x; 1.1505x over previous
//
#include <hip/hip_runtime.h>
#include <hip/hip_bf16.h>

// IsometricLoss: loss = (1/N) * sum_{i,m} r[i,m] * max(||X_i||^2 + ||mu_m||^2 - 2 X_i.mu_m, 0)
// N=131072, M=128, D=128, fp32 in, fp32 scalar out.
//
// R5: zero-barrier, zero-LDS hot path. Each wave owns a 32-mu slice (A=mus in
// regs) and loads X fragments directly from global (lane=row, 2 lanes/line).
// All loads in an iteration are independent and issue before first use; no
// cross-wave coupling -> no convoys. VGPR-disciplined: 4-deep X pipeline,
// __launch_bounds__(256,3) (170 cap) -- spills are the proven catastrophic
// failure mode (R2: +16MB scratch, R4: +73MB), occupancy is secondary.

typedef __attribute__((ext_vector_type(8)))  short  short8;   // 8 bf16 (MFMA A/B frag)
typedef __attribute__((ext_vector_type(16))) float  float16v; // MFMA 32x32 accumulator

#if defined(__has_builtin)
#if __has_builtin(__builtin_amdgcn_cvt_pk_bf16_f32)
#define HAVE_PK_BF16 1
#endif
#endif

__device__ __forceinline__ unsigned int pk_bf16(float x, float y) {
#ifdef HAVE_PK_BF16
    typedef __attribute__((ext_vector_type(2))) __bf16 bf16x2;
    bf16x2 p = __builtin_amdgcn_cvt_pk_bf16_f32(x, y);
    return __builtin_bit_cast(unsigned int, p);
#else
    unsigned int ux = __float_as_uint(x);
    unsigned int uy = __float_as_uint(y);
    ux += 0x7fffu + ((ux >> 16) & 1u);
    uy += 0x7fffu + ((uy >> 16) & 1u);
    return (ux >> 16) | (uy & 0xffff0000u);
#endif
}

__global__ void zero_ws_kernel(float* ws) { ws[threadIdx.x] = 0.0f; }  // 64 buckets

__global__ void final_reduce_kernel(const float* ws, float* out) {
    const int lane = threadIdx.x;  // 64 threads
    float t = ws[lane];
    #pragma unroll
    for (int off = 32; off > 0; off >>= 1) t += __shfl_down(t, off);
    if (lane == 0) out[0] = t * (1.0f / 131072.0f);
}

__global__ __launch_bounds__(256, 3)
void isoloss_kernel(const float* __restrict__ X,
                    const float* __restrict__ r,
                    const float* __restrict__ mus,
                    float* __restrict__ ws)
{
    const int tid  = threadIdx.x;
    const int wave = tid >> 6;       // 0..3 -> which 32-mu slice this wave owns
    const int lane = tid & 63;
    const int col  = lane & 31;      // row index within group (D n-dim) / mu (A m-dim)
    const int half = lane >> 5;      // which k-half this lane covers

    __shared__ float wsum[4];

    // ---- one-time: A fragments = this wave's 32 mus (regs) + exact fp32 mu2 ----
    // A[m=col][k = half*8 + ks*16 + j] = mus[wave*32+col][...]
    short8 bfrag[8];
    float mu2p = 0.0f;
    {
        const float* mrow = mus + (size_t)(wave * 32 + col) * 128 + half * 8;
        #pragma unroll
        for (int ks = 0; ks < 8; ++ks) {
            const float4 a = *(const float4*)(mrow + ks * 16);
            const float4 b = *(const float4*)(mrow + ks * 16 + 4);
            mu2p += a.x*a.x + a.y*a.y + a.z*a.z + a.w*a.w
                  + b.x*b.x + b.y*b.y + b.z*b.z + b.w*b.w;
            union { short8 s8; uint4 u4; } u;
            u.u4.x = pk_bf16(a.x, a.y);
            u.u4.y = pk_bf16(a.z, a.w);
            u.u4.z = pk_bf16(b.x, b.y);
            u.u4.w = pk_bf16(b.z, b.w);
            bfrag[ks] = u.s8;
        }
    }
    const float mu2 = mu2p + __shfl_xor(mu2p, 32);  // lane holds mu2[wave*32+col]
    // epilogue needs mu2 for mus {q*8 + half*4 + j}: gather once via shuffles
    float4 mu2q[4];
    #pragma unroll
    for (int q = 0; q < 4; ++q) {
        mu2q[q].x = __shfl(mu2, q * 8 + half * 4 + 0);
        mu2q[q].y = __shfl(mu2, q * 8 + half * 4 + 1);
        mu2q[q].z = __shfl(mu2, q * 8 + half * 4 + 2);
        mu2q[q].w = __shfl(mu2, q * 8 + half * 4 + 3);
    }

    float s = 0.0f;

    for (int g = blockIdx.x; g < 4096; g += gridDim.x) {
        const int rowbase = g * 32;
        // B[k][n=col] = X[rowbase+col][k], k = half*8 + ks*16 + j
        const float* xp = X + (size_t)(rowbase + col) * 128 + half * 8;
        const float* rp = r + (size_t)(rowbase + col) * 128 + wave * 32 + half * 4;

        // ---- issue 12 independent loads before any use: X ks=0..3 + all r ----
        float4 xa[4], xb[4];
        #pragma unroll
        for (int j = 0; j < 4; ++j) {
            xa[j] = *(const float4*)(xp + j * 16);
            xb[j] = *(const float4*)(xp + j * 16 + 4);
        }
        float4 rv[4];
        #pragma unroll
        for (int q = 0; q < 4; ++q)
            rv[q] = *(const float4*)(rp + q * 8);

        // ---- 8x MFMA, 4-deep rotating X pipeline (8 float4 live max) ----
        float16v acc = {};
        float p = 0.0f;
        #pragma unroll
        for (int ks = 0; ks < 8; ++ks) {
            const float4 a = xa[ks & 3];
            const float4 b = xb[ks & 3];
            if (ks < 4) {  // refill slot with ks+4 while current converts/MFMAs
                xa[ks & 3] = *(const float4*)(xp + (ks + 4) * 16);
                xb[ks & 3] = *(const float4*)(xp + (ks + 4) * 16 + 4);
            }
            p += a.x*a.x + a.y*a.y + a.z*a.z + a.w*a.w
               + b.x*b.x + b.y*b.y + b.z*b.z + b.w*b.w;
            union { short8 s8; uint4 u4; } u;
            u.u4.x = pk_bf16(a.x, a.y);
            u.u4.y = pk_bf16(a.z, a.w);
            u.u4.z = pk_bf16(b.x, b.y);
            u.u4.w = pk_bf16(b.z, b.w);
            acc = __builtin_amdgcn_mfma_f32_32x32x16_bf16(bfrag[ks], u.s8, acc, 0, 0, 0);
        }
        // exact x2 for row rowbase+col: combine this lane's k-half with the other
        const float x2v = p + __shfl_xor(p, 32);

        // ---- epilogue: D[mu][i], i=col, mu = wave*32 + q*8 + half*4 + (reg&3) ----
        #pragma unroll
        for (int q = 0; q < 4; ++q) {
            const float4 rq = rv[q];
            const float4 m2 = mu2q[q];
            s += rq.x * fmaxf(x2v + m2.x - 2.0f * acc[q * 4 + 0], 0.0f);
            s += rq.y * fmaxf(x2v + m2.y - 2.0f * acc[q * 4 + 1], 0.0f);
            s += rq.z * fmaxf(x2v + m2.z - 2.0f * acc[q * 4 + 2], 0.0f);
            s += rq.w * fmaxf(x2v + m2.w - 2.0f * acc[q * 4 + 3], 0.0f);
        }
    }

    // ---- reduce: wave shuffle -> block -> bucketed atomic ----
    #pragma unroll
    for (int off = 32; off > 0; off >>= 1) s += __shfl_down(s, off);
    if (lane == 0) wsum[wave] = s;
    __syncthreads();
    if (tid == 0)
        atomicAdd(&ws[blockIdx.x & 63], wsum[0] + wsum[1] + wsum[2] + wsum[3]);
}

extern "C" void kernel_launch(void* const* d_in, const int* in_sizes, int n_in,
                              void* d_out, int out_size, void* d_ws, size_t ws_size,
                              hipStream_t stream) {
    const float* X   = (const float*)d_in[0];   // [131072, 128]
    const float* r   = (const float*)d_in[1];   // [131072, 128]
    const float* mus = (const float*)d_in[2];   // [128, 128]
    float* out = (float*)d_out;                 // scalar
    float* ws  = (float*)d_ws;                  // 64 partial buckets

    zero_ws_kernel<<<1, 64, 0, stream>>>(ws);
    isoloss_kernel<<<1024, 256, 0, stream>>>(X, r, mus, ws);
    final_reduce_kernel<<<1, 64, 0, stream>>>(ws, out);
}

// Round 6
// 164.644 us; speedup vs baseline: 1.1535x; 1.0026x over previous
//
#include <hip/hip_runtime.h>
#include <hip/hip_bf16.h>

// IsometricLoss: loss = (1/N) * sum_{i,m} r[i,m] * max(||X_i||^2 + ||mu_m||^2 - 2 X_i.mu_m, 0)
// N=131072, M=128, D=128, fp32 in, fp32 scalar out.
//
// R6 = R5 (zero-barrier, zero-LDS, spill-free) + forced memory-level parallelism.
// R5's failure: VGPR_Count=68 proved the scheduler sank the 20 iteration loads
// to their uses -> MLP~2, serialized ~900-cyc latencies. Fix: issue ALL loads
// (16 X float4 + 4 r float4) as one block, then __builtin_amdgcn_sched_barrier(0)
// so nothing crosses; live set ~145 VGPR < 170 cap at __launch_bounds__(256,3).

typedef __attribute__((ext_vector_type(8)))  short  short8;   // 8 bf16 (MFMA A/B frag)
typedef __attribute__((ext_vector_type(16))) float  float16v; // MFMA 32x32 accumulator

#if defined(__has_builtin)
#if __has_builtin(__builtin_amdgcn_cvt_pk_bf16_f32)
#define HAVE_PK_BF16 1
#endif
#endif

__device__ __forceinline__ unsigned int pk_bf16(float x, float y) {
#ifdef HAVE_PK_BF16
    typedef __attribute__((ext_vector_type(2))) __bf16 bf16x2;
    bf16x2 p = __builtin_amdgcn_cvt_pk_bf16_f32(x, y);
    return __builtin_bit_cast(unsigned int, p);
#else
    unsigned int ux = __float_as_uint(x);
    unsigned int uy = __float_as_uint(y);
    ux += 0x7fffu + ((ux >> 16) & 1u);
    uy += 0x7fffu + ((uy >> 16) & 1u);
    return (ux >> 16) | (uy & 0xffff0000u);
#endif
}

__global__ void zero_ws_kernel(float* ws) { ws[threadIdx.x] = 0.0f; }  // 64 buckets

__global__ void final_reduce_kernel(const float* ws, float* out) {
    const int lane = threadIdx.x;  // 64 threads
    float t = ws[lane];
    #pragma unroll
    for (int off = 32; off > 0; off >>= 1) t += __shfl_down(t, off);
    if (lane == 0) out[0] = t * (1.0f / 131072.0f);
}

__global__ __launch_bounds__(256, 3)
void isoloss_kernel(const float* __restrict__ X,
                    const float* __restrict__ r,
                    const float* __restrict__ mus,
                    float* __restrict__ ws)
{
    const int tid  = threadIdx.x;
    const int wave = tid >> 6;       // 0..3 -> which 32-mu slice this wave owns
    const int lane = tid & 63;
    const int col  = lane & 31;      // row index within group (D n-dim) / mu (A m-dim)
    const int half = lane >> 5;      // which k-half this lane covers

    __shared__ float wsum[4];

    // ---- one-time: A fragments = this wave's 32 mus (regs) + exact fp32 mu2 ----
    short8 bfrag[8];
    float mu2p = 0.0f;
    {
        const float* mrow = mus + (size_t)(wave * 32 + col) * 128 + half * 8;
        #pragma unroll
        for (int ks = 0; ks < 8; ++ks) {
            const float4 a = *(const float4*)(mrow + ks * 16);
            const float4 b = *(const float4*)(mrow + ks * 16 + 4);
            mu2p += a.x*a.x + a.y*a.y + a.z*a.z + a.w*a.w
                  + b.x*b.x + b.y*b.y + b.z*b.z + b.w*b.w;
            union { short8 s8; uint4 u4; } u;
            u.u4.x = pk_bf16(a.x, a.y);
            u.u4.y = pk_bf16(a.z, a.w);
            u.u4.z = pk_bf16(b.x, b.y);
            u.u4.w = pk_bf16(b.z, b.w);
            bfrag[ks] = u.s8;
        }
    }
    const float mu2 = mu2p + __shfl_xor(mu2p, 32);  // lane holds mu2[wave*32+col]
    float4 mu2q[4];
    #pragma unroll
    for (int q = 0; q < 4; ++q) {
        mu2q[q].x = __shfl(mu2, q * 8 + half * 4 + 0);
        mu2q[q].y = __shfl(mu2, q * 8 + half * 4 + 1);
        mu2q[q].z = __shfl(mu2, q * 8 + half * 4 + 2);
        mu2q[q].w = __shfl(mu2, q * 8 + half * 4 + 3);
    }

    float s = 0.0f;

    for (int g = blockIdx.x; g < 4096; g += gridDim.x) {
        const int rowbase = g * 32;
        // B[k][n=col] = X[rowbase+col][k], k = half*8 + ks*16 + j
        const float* xp = X + (size_t)(rowbase + col) * 128 + half * 8;
        const float* rp = r + (size_t)(rowbase + col) * 128 + wave * 32 + half * 4;

        // ---- issue ALL 20 iteration loads, then fence the scheduler ----
        float4 xa[8], xb[8];
        #pragma unroll
        for (int ks = 0; ks < 8; ++ks) {
            xa[ks] = *(const float4*)(xp + ks * 16);
            xb[ks] = *(const float4*)(xp + ks * 16 + 4);
        }
        float4 rv[4];
        #pragma unroll
        for (int q = 0; q < 4; ++q)
            rv[q] = *(const float4*)(rp + q * 8);

        __builtin_amdgcn_sched_barrier(0);  // nothing crosses: loads stay issued up here

        // ---- 8x MFMA + exact fp32 x2 partial ----
        float16v acc = {};
        float p = 0.0f;
        #pragma unroll
        for (int ks = 0; ks < 8; ++ks) {
            const float4 a = xa[ks];
            const float4 b = xb[ks];
            p += a.x*a.x + a.y*a.y + a.z*a.z + a.w*a.w
               + b.x*b.x + b.y*b.y + b.z*b.z + b.w*b.w;
            union { short8 s8; uint4 u4; } u;
            u.u4.x = pk_bf16(a.x, a.y);
            u.u4.y = pk_bf16(a.z, a.w);
            u.u4.z = pk_bf16(b.x, b.y);
            u.u4.w = pk_bf16(b.z, b.w);
            acc = __builtin_amdgcn_mfma_f32_32x32x16_bf16(bfrag[ks], u.s8, acc, 0, 0, 0);
        }
        const float x2v = p + __shfl_xor(p, 32);  // exact x2[rowbase+col]

        // ---- epilogue: D[mu][i], i=col, mu = wave*32 + q*8 + half*4 + (reg&3) ----
        #pragma unroll
        for (int q = 0; q < 4; ++q) {
            const float4 rq = rv[q];
            const float4 m2 = mu2q[q];
            s += rq.x * fmaxf(x2v + m2.x - 2.0f * acc[q * 4 + 0], 0.0f);
            s += rq.y * fmaxf(x2v + m2.y - 2.0f * acc[q * 4 + 1], 0.0f);
            s += rq.z * fmaxf(x2v + m2.z - 2.0f * acc[q * 4 + 2], 0.0f);
            s += rq.w * fmaxf(x2v + m2.w - 2.0f * acc[q * 4 + 3], 0.0f);
        }
    }

    // ---- reduce: wave shuffle -> block -> bucketed atomic ----
    #pragma unroll
    for (int off = 32; off > 0; off >>= 1) s += __shfl_down(s, off);
    if (lane == 0) wsum[wave] = s;
    __syncthreads();
    if (tid == 0)
        atomicAdd(&ws[blockIdx.x & 63], wsum[0] + wsum[1] + wsum[2] + wsum[3]);
}

extern "C" void kernel_launch(void* const* d_in, const int* in_sizes, int n_in,
                              void* d_out, int out_size, void* d_ws, size_t ws_size,
                              hipStream_t stream) {
    const float* X   = (const float*)d_in[0];   // [131072, 128]
    const float* r   = (const float*)d_in[1];   // [131072, 128]
    const float* mus = (const float*)d_in[2];   // [128, 128]
    float* out = (float*)d_out;                 // scalar
    float* ws  = (float*)d_ws;                  // 64 partial buckets

    zero_ws_kernel<<<1, 64, 0, stream>>>(ws);
    isoloss_kernel<<<1024, 256, 0, stream>>>(X, r, mus, ws);
    final_reduce_kernel<<<1, 64, 0, stream>>>(ws, out);
}

// Round 7
// 151.513 us; speedup vs baseline: 1.2534x; 1.0867x over previous
//
#include <hip/hip_runtime.h>
#include <hip/hip_bf16.h>

// IsometricLoss: loss = (1/N) * sum_{i,m} r[i,m] * max(||X_i||^2 + ||mu_m||^2 - 2 X_i.mu_m, 0)
// N=131072, M=128, D=128, fp32 in, fp32 scalar out.
//
// R7: global_load_lds DMA pipeline. R1-R6 proved: (a) compiler refuses >2-4
// VGPR-held global loads in flight per wave (VGPR_Count 60-68 every round),
// (b) __syncthreads' fence forces vmcnt(0) drains. Fix both: fire-and-forget
// DMA to LDS (zero VGPR per outstanding load, 16 KB in flight per wave),
// double-buffered with s_waitcnt vmcnt(8) (never 0) + raw s_barrier (no fence
// -> no drain on gfx950's back-off barrier). LDS image XOR-swizzled at 16-B
// granules AT DMA TIME (we choose each lane's source granule) so transposed
// fragment reads and r reads are exactly conflict-free.

typedef __attribute__((ext_vector_type(8)))  short  short8;   // 8 bf16 (MFMA A/B frag)
typedef __attribute__((ext_vector_type(16))) float  float16v; // MFMA 32x32 accumulator

#if defined(__has_builtin)
#if __has_builtin(__builtin_amdgcn_cvt_pk_bf16_f32)
#define HAVE_PK_BF16 1
#endif
#endif

__device__ __forceinline__ unsigned int pk_bf16(float x, float y) {
#ifdef HAVE_PK_BF16
    typedef __attribute__((ext_vector_type(2))) __bf16 bf16x2;
    bf16x2 p = __builtin_amdgcn_cvt_pk_bf16_f32(x, y);
    return __builtin_bit_cast(unsigned int, p);
#else
    unsigned int ux = __float_as_uint(x);
    unsigned int uy = __float_as_uint(y);
    ux += 0x7fffu + ((ux >> 16) & 1u);
    uy += 0x7fffu + ((uy >> 16) & 1u);
    return (ux >> 16) | (uy & 0xffff0000u);
#endif
}

#define AS1 __attribute__((address_space(1)))
#define AS3 __attribute__((address_space(3)))

// 16 B per lane, dest = wave-uniform LDS base + lane*16 (HW-defined scatter)
__device__ __forceinline__ void dma16(const void* g, void* l) {
    __builtin_amdgcn_global_load_lds((const AS1 void*)g, (AS3 void*)l, 16, 0, 0);
}

// waitcnt imm: vmcnt[3:0]@[3:0], expcnt@[6:4], lgkmcnt@[11:8], vmcnt[5:4]@[15:14]
__device__ __forceinline__ void wait_vm8() { __builtin_amdgcn_s_waitcnt(0x0F78); }  // vm=8, lgkm/exp free
__device__ __forceinline__ void wait_vm0() { __builtin_amdgcn_s_waitcnt(0x0F70); }  // vm=0, lgkm/exp free
__device__ __forceinline__ void barrier_nodrain() {
    asm volatile("" ::: "memory");           // compiler-only fence (no codegen)
    __builtin_amdgcn_s_barrier();            // no HW/compiler vmcnt drain (back-off barrier)
    asm volatile("" ::: "memory");
}

__global__ void zero_ws_kernel(float* ws) { ws[threadIdx.x] = 0.0f; }  // 64 buckets

__global__ void final_reduce_kernel(const float* ws, float* out) {
    const int lane = threadIdx.x;  // 64 threads
    float t = ws[lane];
    #pragma unroll
    for (int off = 32; off > 0; off >>= 1) t += __shfl_down(t, off);
    if (lane == 0) out[0] = t * (1.0f / 131072.0f);
}

__global__ __launch_bounds__(256, 2)
void isoloss_kernel(const float* __restrict__ X,
                    const float* __restrict__ r,
                    const float* __restrict__ mus,
                    float* __restrict__ ws)
{
    const int tid  = threadIdx.x;
    const int wave = tid >> 6;       // 0..3 -> which 32-mu slice this wave owns
    const int lane = tid & 63;
    const int col  = lane & 31;      // row index i within group / mu within slice
    const int half = lane >> 5;      // k-half this lane covers

    // 4 DISTINCT objects (not one indexed array): lets LLVM's per-object
    // LDS-DMA alias tracking avoid spurious vmcnt waits on the consume buffer.
    __shared__ __align__(16) unsigned char ldsX0[16384];
    __shared__ __align__(16) unsigned char ldsX1[16384];
    __shared__ __align__(16) unsigned char ldsR0[16384];
    __shared__ __align__(16) unsigned char ldsR1[16384];
    __shared__ float wsum[4];

    // ---- one-time: A fragments = this wave's 32 mus (regs) + exact fp32 mu2 ----
    short8 bfrag[8];
    float mu2p = 0.0f;
    {
        const float* mrow = mus + (size_t)(wave * 32 + col) * 128 + half * 8;
        #pragma unroll
        for (int ks = 0; ks < 8; ++ks) {
            const float4 a = *(const float4*)(mrow + ks * 16);
            const float4 b = *(const float4*)(mrow + ks * 16 + 4);
            mu2p += a.x*a.x + a.y*a.y + a.z*a.z + a.w*a.w
                  + b.x*b.x + b.y*b.y + b.z*b.z + b.w*b.w;
            union { short8 s8; uint4 u4; } u;
            u.u4.x = pk_bf16(a.x, a.y);
            u.u4.y = pk_bf16(a.z, a.w);
            u.u4.z = pk_bf16(b.x, b.y);
            u.u4.w = pk_bf16(b.z, b.w);
            bfrag[ks] = u.s8;
        }
    }
    const float mu2 = mu2p + __shfl_xor(mu2p, 32);  // lane holds mu2[wave*32+col]
    float4 mu2q[4];
    #pragma unroll
    for (int q = 0; q < 4; ++q) {
        mu2q[q].x = __shfl(mu2, q * 8 + half * 4 + 0);
        mu2q[q].y = __shfl(mu2, q * 8 + half * 4 + 1);
        mu2q[q].z = __shfl(mu2, q * 8 + half * 4 + 2);
        mu2q[q].w = __shfl(mu2, q * 8 + half * 4 + 3);
    }

    // ---- per-lane DMA source byte offsets within one 16 KB group ----
    // LDS granule position p = (wave*4+t)*64 + lane holds global granule
    // (row = p>>5, c = (lane&31) ^ row)  => LDS image (row,c) at row*32+(c^row).
    int goff[4];
    #pragma unroll
    for (int t = 0; t < 4; ++t) {
        const int p   = (wave * 4 + t) * 64 + lane;
        const int row = p >> 5;                          // 0..31
        goff[t] = row * 512 + (((lane & 31) ^ row) << 4);
    }

    const int   g0 = blockIdx.x;            // groups g0 + i*512, i = 0..7
    const char* Xc = (const char*)X;
    const char* Rc = (const char*)r;

    // ---- prologue: DMA group g0 into buffer 0 (8 instr, fire-and-forget) ----
    {
        const char* xg = Xc + (size_t)g0 * 16384;
        const char* rg = Rc + (size_t)g0 * 16384;
        #pragma unroll
        for (int t = 0; t < 4; ++t) {
            dma16(xg + goff[t], ldsX0 + (wave * 4 + t) * 1024);
            dma16(rg + goff[t], ldsR0 + (wave * 4 + t) * 1024);
        }
    }

    float s = 0.0f;

    #pragma unroll
    for (int i = 0; i < 8; ++i) {
        unsigned char* bx  = (i & 1) ? ldsX1 : ldsX0;   // consume buffer
        unsigned char* br  = (i & 1) ? ldsR1 : ldsR0;
        unsigned char* bxn = (i & 1) ? ldsX0 : ldsX1;   // prefetch buffer
        unsigned char* brn = (i & 1) ? ldsR0 : ldsR1;

        if (i < 7) {
            const int gn = g0 + (i + 1) * 512;
            const char* xg = Xc + (size_t)gn * 16384;
            const char* rg = Rc + (size_t)gn * 16384;
            #pragma unroll
            for (int t = 0; t < 4; ++t) {
                dma16(xg + goff[t], bxn + (wave * 4 + t) * 1024);
                dma16(rg + goff[t], brn + (wave * 4 + t) * 1024);
            }
            wait_vm8();   // drain group i's DMAs; the 8 just-issued stay in flight
        } else {
            wait_vm0();   // last group: nothing newer outstanding
        }
        barrier_nodrain();  // every wave waited for its own i-DMAs => buffer complete

        // ---- consume group i: 8x MFMA + exact fp32 x2 ----
        float16v acc = {};
        float p = 0.0f;
        #pragma unroll
        for (int ks = 0; ks < 8; ++ks) {
            const int cc = ks * 4 + half * 2;
            const float4 f0 = *(const float4*)(bx + col * 512 + (((cc    ) ^ col) << 4));
            const float4 f1 = *(const float4*)(bx + col * 512 + (((cc + 1) ^ col) << 4));
            p += f0.x*f0.x + f0.y*f0.y + f0.z*f0.z + f0.w*f0.w
               + f1.x*f1.x + f1.y*f1.y + f1.z*f1.z + f1.w*f1.w;
            union { short8 s8; uint4 u4; } u;
            u.u4.x = pk_bf16(f0.x, f0.y);
            u.u4.y = pk_bf16(f0.z, f0.w);
            u.u4.z = pk_bf16(f1.x, f1.y);
            u.u4.w = pk_bf16(f1.z, f1.w);
            acc = __builtin_amdgcn_mfma_f32_32x32x16_bf16(bfrag[ks], u.s8, acc, 0, 0, 0);
        }
        const float x2v = p + __shfl_xor(p, 32);  // exact x2[row = g*32+col]

        // ---- epilogue: D[mu][i], i=col; r from swizzled LDS (conflict-free) ----
        #pragma unroll
        for (int q = 0; q < 4; ++q) {
            const int cq = (wave * 8 + half + q * 2) ^ col;
            const float4 rq = *(const float4*)(br + col * 512 + (cq << 4));
            const float4 m2 = mu2q[q];
            s += rq.x * fmaxf(x2v + m2.x - 2.0f * acc[q * 4 + 0], 0.0f);
            s += rq.y * fmaxf(x2v + m2.y - 2.0f * acc[q * 4 + 1], 0.0f);
            s += rq.z * fmaxf(x2v + m2.z - 2.0f * acc[q * 4 + 2], 0.0f);
            s += rq.w * fmaxf(x2v + m2.w - 2.0f * acc[q * 4 + 3], 0.0f);
        }

        if (i < 7) barrier_nodrain();  // all waves done reading buf before re-DMA
    }

    // ---- reduce: wave shuffle -> block -> bucketed atomic ----
    #pragma unroll
    for (int off = 32; off > 0; off >>= 1) s += __shfl_down(s, off);
    if (lane == 0) wsum[wave] = s;
    __syncthreads();
    if (tid == 0)
        atomicAdd(&ws[blockIdx.x & 63], wsum[0] + wsum[1] + wsum[2] + wsum[3]);
}

extern "C" void kernel_launch(void* const* d_in, const int* in_sizes, int n_in,
                              void* d_out, int out_size, void* d_ws, size_t ws_size,
                              hipStream_t stream) {
    const float* X   = (const float*)d_in[0];   // [131072, 128]
    const float* r   = (const float*)d_in[1];   // [131072, 128]
    const float* mus = (const float*)d_in[2];   // [128, 128]
    float* out = (float*)d_out;                 // scalar
    float* ws  = (float*)d_ws;                  // 64 partial buckets

    zero_ws_kernel<<<1, 64, 0, stream>>>(ws);
    // grid 512 = exactly 2 blocks/CU (64 KB LDS each); 8 groups per block
    isoloss_kernel<<<512, 256, 0, stream>>>(X, r, mus, ws);
    final_reduce_kernel<<<1, 64, 0, stream>>>(ws, out);
}